// Round 1
// baseline (1777.380 us; speedup 1.0000x reference)
//
#include <hip/hip_runtime.h>

#define NROWS 65536
#define DDIM  256
#define KCODES 4096

#define BM 128
#define BN 128
#define KC 16
#define LDT 132   // padded LDS row stride (floats), keeps 16B alignment

// ---------------- Kernel 1: codebook squared norms ----------------
__global__ void cnorm_kernel(const float* __restrict__ cb, float* __restrict__ cnorm) {
    const int wave = threadIdx.x >> 6;
    const int lane = threadIdx.x & 63;
    const int code = blockIdx.x * 4 + wave;
    const float4 v = *reinterpret_cast<const float4*>(cb + (size_t)code * DDIM + lane * 4);
    float s = v.x * v.x + v.y * v.y + v.z * v.z + v.w * v.w;
    #pragma unroll
    for (int off = 32; off; off >>= 1) s += __shfl_down(s, off);
    if (lane == 0) cnorm[code] = s;
}

// ---------------- Kernel 2: fused GEMM + online argmin ----------------
__global__ __launch_bounds__(256) void argmin_kernel(
    const float* __restrict__ z, const float* __restrict__ cb,
    const float* __restrict__ cnorm, int* __restrict__ out_idx)
{
    __shared__ float As[KC][LDT];
    __shared__ float Bs[KC][LDT];

    const int tid  = threadIdx.x;
    const int tx   = tid & 15;   // code group (8 codes)
    const int ty   = tid >> 4;   // row group  (8 rows)
    const int row0 = blockIdx.x * BM;

    // staging decomposition: 256 threads stage 128 rows x 16 k (x2 halves)
    const int srow = tid >> 2;          // 0..63
    const int sg   = (tid & 3) * 4;     // k sub-offset 0,4,8,12

    float bestv[8];
    int   besti[8];
    #pragma unroll
    for (int i = 0; i < 8; ++i) { bestv[i] = 3.402823466e38f; besti[i] = 0; }

    for (int ct = 0; ct < KCODES; ct += BN) {
        float acc[8][8];
        #pragma unroll
        for (int i = 0; i < 8; ++i)
            #pragma unroll
            for (int j = 0; j < 8; ++j) acc[i][j] = 0.f;

        for (int kc = 0; kc < DDIM; kc += KC) {
            __syncthreads();
            {
                const float* za = z  + (size_t)(row0 + srow) * DDIM + kc + sg;
                const float* ba = cb + (size_t)(ct   + srow) * DDIM + kc + sg;
                float4 a0 = *reinterpret_cast<const float4*>(za);
                float4 a1 = *reinterpret_cast<const float4*>(za + (size_t)64 * DDIM);
                float4 b0 = *reinterpret_cast<const float4*>(ba);
                float4 b1 = *reinterpret_cast<const float4*>(ba + (size_t)64 * DDIM);
                As[sg + 0][srow]      = a0.x; As[sg + 1][srow]      = a0.y;
                As[sg + 2][srow]      = a0.z; As[sg + 3][srow]      = a0.w;
                As[sg + 0][srow + 64] = a1.x; As[sg + 1][srow + 64] = a1.y;
                As[sg + 2][srow + 64] = a1.z; As[sg + 3][srow + 64] = a1.w;
                Bs[sg + 0][srow]      = b0.x; Bs[sg + 1][srow]      = b0.y;
                Bs[sg + 2][srow]      = b0.z; Bs[sg + 3][srow]      = b0.w;
                Bs[sg + 0][srow + 64] = b1.x; Bs[sg + 1][srow + 64] = b1.y;
                Bs[sg + 2][srow + 64] = b1.z; Bs[sg + 3][srow + 64] = b1.w;
            }
            __syncthreads();
            #pragma unroll
            for (int k = 0; k < KC; ++k) {
                float4 a0 = *reinterpret_cast<const float4*>(&As[k][ty * 8]);
                float4 a1 = *reinterpret_cast<const float4*>(&As[k][ty * 8 + 4]);
                float4 b0 = *reinterpret_cast<const float4*>(&Bs[k][tx * 8]);
                float4 b1 = *reinterpret_cast<const float4*>(&Bs[k][tx * 8 + 4]);
                float av[8] = {a0.x, a0.y, a0.z, a0.w, a1.x, a1.y, a1.z, a1.w};
                float bv[8] = {b0.x, b0.y, b0.z, b0.w, b1.x, b1.y, b1.z, b1.w};
                #pragma unroll
                for (int i = 0; i < 8; ++i)
                    #pragma unroll
                    for (int j = 0; j < 8; ++j)
                        acc[i][j] = fmaf(av[i], bv[j], acc[i][j]);
            }
        }

        // finalize this code tile: dist ranking value = cnorm - 2*dot (row-constant ||z||^2 dropped)
        float cn[8];
        {
            float4 c0 = *reinterpret_cast<const float4*>(cnorm + ct + tx * 8);
            float4 c1 = *reinterpret_cast<const float4*>(cnorm + ct + tx * 8 + 4);
            cn[0] = c0.x; cn[1] = c0.y; cn[2] = c0.z; cn[3] = c0.w;
            cn[4] = c1.x; cn[5] = c1.y; cn[6] = c1.z; cn[7] = c1.w;
        }
        #pragma unroll
        for (int i = 0; i < 8; ++i) {
            float v  = fmaf(-2.f, acc[i][0], cn[0]);
            int   ix = ct + tx * 8;
            #pragma unroll
            for (int j = 1; j < 8; ++j) {
                float t = fmaf(-2.f, acc[i][j], cn[j]);
                if (t < v) { v = t; ix = ct + tx * 8 + j; }   // strict < : first-min wins
            }
            // reduce across the 16 threads (consecutive lanes) sharing this row group
            #pragma unroll
            for (int m = 1; m < 16; m <<= 1) {
                float ov = __shfl_xor(v, m);
                int   oi = __shfl_xor(ix, m);
                if (ov < v || (ov == v && oi < ix)) { v = ov; ix = oi; }
            }
            if (v < bestv[i] || (v == bestv[i] && ix < besti[i])) { bestv[i] = v; besti[i] = ix; }
        }
    }

    if (tx == 0) {
        #pragma unroll
        for (int i = 0; i < 8; ++i) out_idx[row0 + ty * 8 + i] = besti[i];
    }
}

// ---------------- Kernel 3: gather + straight-through output + loss partials ----------------
__global__ void gather_loss_kernel(const float* __restrict__ z, const float* __restrict__ cb,
                                   const int* __restrict__ idx, float* __restrict__ out,
                                   float* __restrict__ partials)
{
    const int wave = threadIdx.x >> 6;
    const int lane = threadIdx.x & 63;
    const int row  = blockIdx.x * 4 + wave;
    const int k    = idx[row];

    const size_t zo = (size_t)row * DDIM + lane * 4;
    float4 zv = *reinterpret_cast<const float4*>(z  + zo);
    float4 cv = *reinterpret_cast<const float4*>(cb + (size_t)k * DDIM + lane * 4);
    float4 d;
    d.x = cv.x - zv.x; d.y = cv.y - zv.y; d.z = cv.z - zv.z; d.w = cv.w - zv.w;
    float4 o;
    o.x = zv.x + d.x; o.y = zv.y + d.y; o.z = zv.z + d.z; o.w = zv.w + d.w;  // z + (z_q - z)
    *reinterpret_cast<float4*>(out + zo) = o;

    float s = d.x * d.x + d.y * d.y + d.z * d.z + d.w * d.w;
    #pragma unroll
    for (int off = 32; off; off >>= 1) s += __shfl_down(s, off);

    __shared__ float ps[4];
    if (lane == 0) ps[wave] = s;
    __syncthreads();
    if (threadIdx.x == 0) partials[blockIdx.x] = (ps[0] + ps[1]) + (ps[2] + ps[3]);
}

// ---------------- Kernel 4: loss reduce + finalize ----------------
__global__ void finalize_kernel(const float* __restrict__ partials, float* __restrict__ out_loss)
{
    float s = 0.f;
    for (int i = threadIdx.x; i < 16384; i += 256) s += partials[i];
    #pragma unroll
    for (int off = 32; off; off >>= 1) s += __shfl_down(s, off);
    __shared__ float ws_[4];
    if ((threadIdx.x & 63) == 0) ws_[threadIdx.x >> 6] = s;
    __syncthreads();
    if (threadIdx.x == 0) {
        float t = (ws_[0] + ws_[1]) + (ws_[2] + ws_[3]);
        float m = t / 16777216.f;          // mean over N*D elements
        out_loss[0] = 0.25f * (m + m);     // BETA*(loss_commit + loss_code)
    }
}

extern "C" void kernel_launch(void* const* d_in, const int* in_sizes, int n_in,
                              void* d_out, int out_size, void* d_ws, size_t ws_size,
                              hipStream_t stream)
{
    const float* z  = (const float*)d_in[0];   // [16,4096,256] fp32
    const float* cb = (const float*)d_in[1];   // [4096,256]   fp32
    float* out = (float*)d_out;                // [16*4096*256] + [1]

    char*  wsb      = (char*)d_ws;
    int*   idx      = (int*)wsb;                          // 65536 * 4 = 256 KB
    float* cnorm    = (float*)(wsb + 262144);             // 4096 * 4  = 16 KB
    float* partials = (float*)(wsb + 262144 + 16384);     // 16384 * 4 = 64 KB

    cnorm_kernel<<<KCODES / 4, 256, 0, stream>>>(cb, cnorm);
    argmin_kernel<<<NROWS / BM, 256, 0, stream>>>(z, cb, cnorm, idx);
    gather_loss_kernel<<<NROWS / 4, 256, 0, stream>>>(z, cb, idx, out, partials);
    finalize_kernel<<<1, 256, 0, stream>>>(partials, out + (size_t)NROWS * DDIM);
}

// Round 2
// 389.136 us; speedup vs baseline: 4.5675x; 4.5675x over previous
//
#include <hip/hip_runtime.h>

typedef _Float16 f16;
typedef _Float16 f16x8 __attribute__((ext_vector_type(8)));
typedef float f32x4 __attribute__((ext_vector_type(4)));
typedef unsigned int uint32;
typedef unsigned long long u64;

#define NROWS 65536
#define DDIM  256
#define KCODES 4096
#define THRQ 64u   // 0.25 distance-units * 256 quantization scale

#define WS_CBT      0
#define WS_CNORM    2097152
#define WS_CNS      2113536
#define WS_IDX      2129920
#define WS_LIST     2392064
#define WS_COUNTER  2654208
#define WS_PARTIALS 2654464
#define WS_NEEDED   2720000

__device__ __forceinline__ void gload_lds16(const void* g, void* l) {
    __builtin_amdgcn_global_load_lds(
        (const __attribute__((address_space(1))) unsigned int*)g,
        (__attribute__((address_space(3))) unsigned int*)l, 16, 0, 0);
}

// ---- tile codebook -> fp16 granules [ct16][kc32][code256] ----
__global__ void tile_cb_kernel(const float* __restrict__ cb, f16* __restrict__ cbt) {
    int gid = blockIdx.x * 256 + threadIdx.x;
    int row = gid >> 5, kc = gid & 31;
    const float4* s = (const float4*)(cb + (size_t)row * DDIM + kc * 8);
    float4 a = s[0], b = s[1];
    f16x8 v;
    v[0] = (f16)a.x; v[1] = (f16)a.y; v[2] = (f16)a.z; v[3] = (f16)a.w;
    v[4] = (f16)b.x; v[5] = (f16)b.y; v[6] = (f16)b.z; v[7] = (f16)b.w;
    ((f16x8*)cbt)[((size_t)(row >> 8) * 32 + kc) * 256 + (row & 255)] = v;
}

// ---- codebook norms (fp32 exact) + scaled + counter reset ----
__global__ void cnorm_kernel(const float* __restrict__ cb, float* __restrict__ cnorm,
                             float* __restrict__ cn_s, int* __restrict__ counter) {
    if (blockIdx.x == 0 && threadIdx.x == 0) *counter = 0;
    const int wave = threadIdx.x >> 6;
    const int lane = threadIdx.x & 63;
    const int code = blockIdx.x * 4 + wave;
    const float4 v = *reinterpret_cast<const float4*>(cb + (size_t)code * DDIM + lane * 4);
    float s = v.x * v.x + v.y * v.y + v.z * v.z + v.w * v.w;
    #pragma unroll
    for (int off = 32; off; off >>= 1) s += __shfl_down(s, off);
    if (lane == 0) { cnorm[code] = s; cn_s[code] = 256.f * (s + 1024.f); }
}

// ---- fused fp16 MFMA GEMM + online argmin with margin flagging ----
__global__ __launch_bounds__(256, 2) void argmin_mfma(
    const float* __restrict__ z, const f16* __restrict__ cbt,
    const float* __restrict__ cn_s, int* __restrict__ out_idx,
    int* __restrict__ list, int* __restrict__ counter)
{
    __shared__ __align__(16) char smem[65536];
    const int tid  = threadIdx.x;
    const int lane = tid & 63;
    const int wid  = tid >> 6;
    const int l15  = lane & 15;
    const int g    = lane >> 4;
    const int row0 = blockIdx.x * 64;

    {   // stage A: 64 rows x K=256, fp32->fp16, granule layout [kc32][r64]
        int kc = tid & 31;
        int rb = tid >> 5;
        #pragma unroll
        for (int it = 0; it < 8; ++it) {
            int r = it * 8 + rb;
            const float4* s = (const float4*)(z + (size_t)(row0 + r) * DDIM + kc * 8);
            float4 a = s[0], b = s[1];
            f16x8 v;
            v[0] = (f16)a.x; v[1] = (f16)a.y; v[2] = (f16)a.z; v[3] = (f16)a.w;
            v[4] = (f16)b.x; v[5] = (f16)b.y; v[6] = (f16)b.z; v[7] = (f16)b.w;
            *(f16x8*)(smem + ((kc * 64 + r) << 4)) = v;
        }
    }

    uint32 r1[16], r2[16];
    #pragma unroll
    for (int i = 0; i < 16; ++i) { r1[i] = 0xFFFFFFFFu; r2[i] = 0xFFFFFFFFu; }

    for (int ct = 0; ct < 16; ++ct) {
        f32x4 acc[4][4];
        #pragma unroll
        for (int i = 0; i < 4; ++i)
            #pragma unroll
            for (int j = 0; j < 4; ++j) acc[i][j] = (f32x4){0.f, 0.f, 0.f, 0.f};

        for (int ks = 0; ks < 4; ++ks) {
            __syncthreads();
            {
                const char* src = (const char*)cbt + (((size_t)ct * 32 + ks * 8) * 256) * 16;
                char* dst = smem + 32768;
                #pragma unroll
                for (int i = 0; i < 8; ++i)
                    gload_lds16(src + (size_t)i * 4096 + wid * 1024 + (lane << 4),
                                dst + i * 4096 + wid * 1024);
            }
            __syncthreads();

            #pragma unroll
            for (int w = 0; w < 2; ++w) {
                const int kw = ks * 2 + w;
                f16x8 a[4], b[4];
                #pragma unroll
                for (int mi = 0; mi < 4; ++mi)
                    a[mi] = *(const f16x8*)(smem + (kw * 4 + g) * 1024 + mi * 256 + (l15 << 4));
                #pragma unroll
                for (int ni = 0; ni < 4; ++ni)
                    b[ni] = *(const f16x8*)(smem + 32768 + (w * 4 + g) * 4096 + wid * 1024 + ni * 256 + (l15 << 4));
                #pragma unroll
                for (int mi = 0; mi < 4; ++mi)
                    #pragma unroll
                    for (int ni = 0; ni < 4; ++ni)
                        acc[mi][ni] = __builtin_amdgcn_mfma_f32_16x16x32_f16(a[mi], b[ni], acc[mi][ni], 0, 0, 0);
            }
        }

        const int cbase = ct * 256 + wid * 64 + l15;
        const float* cs = cn_s + cbase;
        float c0 = cs[0], c1 = cs[16], c2 = cs[32], c3 = cs[48];
        #pragma unroll
        for (int mi = 0; mi < 4; ++mi) {
            #pragma unroll
            for (int r = 0; r < 4; ++r) {
                uint32 k0 = (((uint32)fmaf(-512.f, acc[mi][0][r], c0)) << 12) | (uint32)cbase;
                uint32 k1 = (((uint32)fmaf(-512.f, acc[mi][1][r], c1)) << 12) | (uint32)(cbase + 16);
                uint32 k2 = (((uint32)fmaf(-512.f, acc[mi][2][r], c2)) << 12) | (uint32)(cbase + 32);
                uint32 k3 = (((uint32)fmaf(-512.f, acc[mi][3][r], c3)) << 12) | (uint32)(cbase + 48);
                uint32 lo1 = min(k0, k1), hi1 = max(k0, k1);
                uint32 lo2 = min(k2, k3), hi2 = max(k2, k3);
                uint32 s1 = min(lo1, lo2);
                uint32 s2 = min(max(lo1, lo2), min(hi1, hi2));
                int q = mi * 4 + r;
                uint32 m2 = min(max(r1[q], s1), min(r2[q], s2));
                r1[q] = min(r1[q], s1);
                r2[q] = m2;
            }
        }
    }

    #pragma unroll
    for (int q = 0; q < 16; ++q) {
        uint32 a1 = r1[q], a2 = r2[q];
        #pragma unroll
        for (int m = 1; m < 16; m <<= 1) {
            uint32 o1 = __shfl_xor(a1, m);
            uint32 o2 = __shfl_xor(a2, m);
            a2 = min(max(a1, o1), min(a2, o2));
            a1 = min(a1, o1);
        }
        r1[q] = a1; r2[q] = a2;
    }

    __syncthreads();
    uint2* arr = (uint2*)smem;
    if (l15 == 0) {
        #pragma unroll
        for (int q = 0; q < 16; ++q)
            arr[(wid * 4 + g) * 16 + q] = make_uint2(r1[q], r2[q]);
    }
    __syncthreads();
    if (tid < 64) {
        int mi = tid >> 4, gg = (tid >> 2) & 3, r = tid & 3;
        int q = mi * 4 + r;
        uint32 a1 = 0xFFFFFFFFu, a2 = 0xFFFFFFFFu;
        #pragma unroll
        for (int w = 0; w < 4; ++w) {
            uint2 v = arr[(w * 4 + gg) * 16 + q];
            a2 = min(max(a1, v.x), min(a2, v.y));
            a1 = min(a1, v.x);
        }
        int row = row0 + mi * 16 + gg * 4 + r;
        out_idx[row] = (int)(a1 & 0xFFFu);
        if (((a2 >> 12) - (a1 >> 12)) <= THRQ) {
            int p = atomicAdd(counter, 1);
            list[p] = row;
        }
    }
}

// ---- exact fp32 re-argmin for flagged rows ----
__global__ __launch_bounds__(256) void refine_kernel(
    const float* __restrict__ z, const float* __restrict__ cb,
    const float* __restrict__ cnorm, const int* __restrict__ list,
    const int* __restrict__ counter, int* __restrict__ out_idx)
{
    __shared__ float zT[256][16];
    __shared__ int rows_s[16];
    __shared__ u64 wred[4][16];
    const int tid = threadIdx.x;
    const int cnt = *counter;

    for (int batch = blockIdx.x; batch * 16 < cnt; batch += gridDim.x) {
        __syncthreads();
        if (tid < 16) {
            int li = batch * 16 + tid;
            rows_s[tid] = list[li < cnt ? li : batch * 16];
        }
        __syncthreads();
        {
            int j = tid & 15, kq = tid >> 4;
            const float* zr = z + (size_t)rows_s[j] * DDIM + kq * 16;
            #pragma unroll
            for (int i = 0; i < 16; ++i) zT[kq * 16 + i][j] = zr[i];
        }
        __syncthreads();

        u64 best[16];
        #pragma unroll
        for (int j = 0; j < 16; ++j) best[j] = ~0ull;

        for (int pass = 0; pass < 4; ++pass) {
            const int c0 = pass * 1024 + tid;
            const float* cbp = cb + (size_t)c0 * DDIM;
            float acc[4][16];
            #pragma unroll
            for (int cc = 0; cc < 4; ++cc)
                #pragma unroll
                for (int j = 0; j < 16; ++j) acc[cc][j] = 0.f;

            for (int k = 0; k < 256; k += 4) {
                float4 q0 = *(const float4*)(cbp + k);
                float4 q1 = *(const float4*)(cbp + 256 * 256 + k);
                float4 q2 = *(const float4*)(cbp + 512 * 256 + k);
                float4 q3 = *(const float4*)(cbp + 768 * 256 + k);
                #pragma unroll
                for (int kk = 0; kk < 4; ++kk) {
                    float4 za = *(const float4*)&zT[k + kk][0];
                    float4 zb = *(const float4*)&zT[k + kk][4];
                    float4 zc = *(const float4*)&zT[k + kk][8];
                    float4 zd = *(const float4*)&zT[k + kk][12];
                    float zv[16] = {za.x, za.y, za.z, za.w, zb.x, zb.y, zb.z, zb.w,
                                    zc.x, zc.y, zc.z, zc.w, zd.x, zd.y, zd.z, zd.w};
                    float qv[4] = {((const float*)&q0)[kk], ((const float*)&q1)[kk],
                                   ((const float*)&q2)[kk], ((const float*)&q3)[kk]};
                    #pragma unroll
                    for (int cc = 0; cc < 4; ++cc)
                        #pragma unroll
                        for (int j = 0; j < 16; ++j)
                            acc[cc][j] = fmaf(qv[cc], zv[j], acc[cc][j]);
                }
            }
            #pragma unroll
            for (int cc = 0; cc < 4; ++cc) {
                int c = c0 + cc * 256;
                float cn = cnorm[c] + 1024.f;
                #pragma unroll
                for (int j = 0; j < 16; ++j) {
                    float v = fmaf(-2.f, acc[cc][j], cn);
                    u64 key = ((u64)__float_as_uint(v) << 12) | (uint32)c;
                    best[j] = key < best[j] ? key : best[j];
                }
            }
        }
        #pragma unroll
        for (int j = 0; j < 16; ++j) {
            u64 b = best[j];
            #pragma unroll
            for (int m = 1; m < 64; m <<= 1) {
                u64 o = __shfl_xor(b, m);
                b = o < b ? o : b;
            }
            if ((tid & 63) == 0) wred[tid >> 6][j] = b;
        }
        __syncthreads();
        if (tid < 16) {
            u64 b = wred[0][tid];
            #pragma unroll
            for (int w = 1; w < 4; ++w) b = wred[w][tid] < b ? wred[w][tid] : b;
            out_idx[rows_s[tid]] = (int)(b & 0xFFFu);
        }
        __syncthreads();
    }
}

// ---- gather + straight-through + loss partials ----
__global__ void gather_loss_kernel(const float* __restrict__ z, const float* __restrict__ cb,
                                   const int* __restrict__ idx, float* __restrict__ out,
                                   float* __restrict__ partials)
{
    const int wave = threadIdx.x >> 6;
    const int lane = threadIdx.x & 63;
    const int row  = blockIdx.x * 4 + wave;
    const int k    = idx[row];

    const size_t zo = (size_t)row * DDIM + lane * 4;
    float4 zv = *reinterpret_cast<const float4*>(z + zo);
    float4 cv = *reinterpret_cast<const float4*>(cb + (size_t)k * DDIM + lane * 4);
    float4 d;
    d.x = cv.x - zv.x; d.y = cv.y - zv.y; d.z = cv.z - zv.z; d.w = cv.w - zv.w;
    float4 o;
    o.x = zv.x + d.x; o.y = zv.y + d.y; o.z = zv.z + d.z; o.w = zv.w + d.w;
    *reinterpret_cast<float4*>(out + zo) = o;

    float s = d.x * d.x + d.y * d.y + d.z * d.z + d.w * d.w;
    #pragma unroll
    for (int off = 32; off; off >>= 1) s += __shfl_down(s, off);

    __shared__ float ps[4];
    if (lane == 0) ps[wave] = s;
    __syncthreads();
    if (threadIdx.x == 0) partials[blockIdx.x] = (ps[0] + ps[1]) + (ps[2] + ps[3]);
}

__global__ void finalize_kernel(const float* __restrict__ partials, float* __restrict__ out_loss)
{
    float s = 0.f;
    for (int i = threadIdx.x; i < 16384; i += 256) s += partials[i];
    #pragma unroll
    for (int off = 32; off; off >>= 1) s += __shfl_down(s, off);
    __shared__ float ws_[4];
    if ((threadIdx.x & 63) == 0) ws_[threadIdx.x >> 6] = s;
    __syncthreads();
    if (threadIdx.x == 0) {
        float t = (ws_[0] + ws_[1]) + (ws_[2] + ws_[3]);
        float m = t / 16777216.f;
        out_loss[0] = 0.25f * (m + m);
    }
}

// ---- fallback: round-1 exact fp32 VALU argmin (known-good) ----
#define BM 128
#define BN 128
#define KC 16
#define LDT 132
__global__ __launch_bounds__(256) void argmin_fallback(
    const float* __restrict__ z, const float* __restrict__ cb,
    const float* __restrict__ cnorm, int* __restrict__ out_idx)
{
    __shared__ float As[KC][LDT];
    __shared__ float Bs[KC][LDT];
    const int tid  = threadIdx.x;
    const int tx   = tid & 15;
    const int ty   = tid >> 4;
    const int row0 = blockIdx.x * BM;
    const int srow = tid >> 2;
    const int sg   = (tid & 3) * 4;

    float bestv[8]; int besti[8];
    #pragma unroll
    for (int i = 0; i < 8; ++i) { bestv[i] = 3.402823466e38f; besti[i] = 0; }

    for (int ct = 0; ct < KCODES; ct += BN) {
        float acc[8][8];
        #pragma unroll
        for (int i = 0; i < 8; ++i)
            #pragma unroll
            for (int j = 0; j < 8; ++j) acc[i][j] = 0.f;
        for (int kc = 0; kc < DDIM; kc += KC) {
            __syncthreads();
            {
                const float* za = z  + (size_t)(row0 + srow) * DDIM + kc + sg;
                const float* ba = cb + (size_t)(ct   + srow) * DDIM + kc + sg;
                float4 a0 = *reinterpret_cast<const float4*>(za);
                float4 a1 = *reinterpret_cast<const float4*>(za + (size_t)64 * DDIM);
                float4 b0 = *reinterpret_cast<const float4*>(ba);
                float4 b1 = *reinterpret_cast<const float4*>(ba + (size_t)64 * DDIM);
                As[sg + 0][srow] = a0.x; As[sg + 1][srow] = a0.y; As[sg + 2][srow] = a0.z; As[sg + 3][srow] = a0.w;
                As[sg + 0][srow + 64] = a1.x; As[sg + 1][srow + 64] = a1.y; As[sg + 2][srow + 64] = a1.z; As[sg + 3][srow + 64] = a1.w;
                Bs[sg + 0][srow] = b0.x; Bs[sg + 1][srow] = b0.y; Bs[sg + 2][srow] = b0.z; Bs[sg + 3][srow] = b0.w;
                Bs[sg + 0][srow + 64] = b1.x; Bs[sg + 1][srow + 64] = b1.y; Bs[sg + 2][srow + 64] = b1.z; Bs[sg + 3][srow + 64] = b1.w;
            }
            __syncthreads();
            #pragma unroll
            for (int k = 0; k < KC; ++k) {
                float4 a0 = *reinterpret_cast<const float4*>(&As[k][ty * 8]);
                float4 a1 = *reinterpret_cast<const float4*>(&As[k][ty * 8 + 4]);
                float4 b0 = *reinterpret_cast<const float4*>(&Bs[k][tx * 8]);
                float4 b1 = *reinterpret_cast<const float4*>(&Bs[k][tx * 8 + 4]);
                float av[8] = {a0.x, a0.y, a0.z, a0.w, a1.x, a1.y, a1.z, a1.w};
                float bv[8] = {b0.x, b0.y, b0.z, b0.w, b1.x, b1.y, b1.z, b1.w};
                #pragma unroll
                for (int i = 0; i < 8; ++i)
                    #pragma unroll
                    for (int j = 0; j < 8; ++j)
                        acc[i][j] = fmaf(av[i], bv[j], acc[i][j]);
            }
        }
        float cn[8];
        float4 c0v = *reinterpret_cast<const float4*>(cnorm + ct + tx * 8);
        float4 c1v = *reinterpret_cast<const float4*>(cnorm + ct + tx * 8 + 4);
        cn[0] = c0v.x; cn[1] = c0v.y; cn[2] = c0v.z; cn[3] = c0v.w;
        cn[4] = c1v.x; cn[5] = c1v.y; cn[6] = c1v.z; cn[7] = c1v.w;
        #pragma unroll
        for (int i = 0; i < 8; ++i) {
            float v = fmaf(-2.f, acc[i][0], cn[0]);
            int ix = ct + tx * 8;
            #pragma unroll
            for (int j = 1; j < 8; ++j) {
                float t = fmaf(-2.f, acc[i][j], cn[j]);
                if (t < v) { v = t; ix = ct + tx * 8 + j; }
            }
            #pragma unroll
            for (int m = 1; m < 16; m <<= 1) {
                float ov = __shfl_xor(v, m);
                int oi = __shfl_xor(ix, m);
                if (ov < v || (ov == v && oi < ix)) { v = ov; ix = oi; }
            }
            if (v < bestv[i] || (v == bestv[i] && ix < besti[i])) { bestv[i] = v; besti[i] = ix; }
        }
    }
    if (tx == 0) {
        #pragma unroll
        for (int i = 0; i < 8; ++i) out_idx[row0 + ty * 8 + i] = besti[i];
    }
}

extern "C" void kernel_launch(void* const* d_in, const int* in_sizes, int n_in,
                              void* d_out, int out_size, void* d_ws, size_t ws_size,
                              hipStream_t stream)
{
    const float* z  = (const float*)d_in[0];
    const float* cb = (const float*)d_in[1];
    float* out = (float*)d_out;
    char* wsb = (char*)d_ws;

    if (ws_size >= WS_NEEDED) {
        f16*   cbt      = (f16*)(wsb + WS_CBT);
        float* cnorm    = (float*)(wsb + WS_CNORM);
        float* cn_s     = (float*)(wsb + WS_CNS);
        int*   idx      = (int*)(wsb + WS_IDX);
        int*   list     = (int*)(wsb + WS_LIST);
        int*   counter  = (int*)(wsb + WS_COUNTER);
        float* partials = (float*)(wsb + WS_PARTIALS);

        tile_cb_kernel<<<512, 256, 0, stream>>>(cb, cbt);
        cnorm_kernel<<<KCODES / 4, 256, 0, stream>>>(cb, cnorm, cn_s, counter);
        argmin_mfma<<<NROWS / 64, 256, 0, stream>>>(z, cbt, cn_s, idx, list, counter);
        refine_kernel<<<512, 256, 0, stream>>>(z, cb, cnorm, list, counter, idx);
        gather_loss_kernel<<<NROWS / 4, 256, 0, stream>>>(z, cb, idx, out, partials);
        finalize_kernel<<<1, 256, 0, stream>>>(partials, out + (size_t)NROWS * DDIM);
    } else {
        int*   idx      = (int*)(wsb + 0);
        float* cnorm    = (float*)(wsb + 262144);
        float* cn_s     = (float*)(wsb + 278528);
        float* partials = (float*)(wsb + 294912);
        int*   counter  = (int*)(wsb + 294912);

        cnorm_kernel<<<KCODES / 4, 256, 0, stream>>>(cb, cnorm, cn_s, counter);
        argmin_fallback<<<NROWS / BM, 256, 0, stream>>>(z, cb, cnorm, idx);
        gather_loss_kernel<<<NROWS / 4, 256, 0, stream>>>(z, cb, idx, out, partials);
        finalize_kernel<<<1, 256, 0, stream>>>(partials, out + (size_t)NROWS * DDIM);
    }
}